// Round 1
// baseline (158.398 us; speedup 1.0000x reference)
//
#include <hip/hip_runtime.h>
#include <math.h>

#define BDIM 256
constexpr int Bn = 64, Sn = 6, Tn = 2000, Cn = 25;
constexpr int NCHUNK = 4;                    // chunks of T per (b,s)
constexpr int TCHUNK = Tn / NCHUNK;          // 500

// ws layout: ws[0..5] = sum_{b,t} nll per string ; ws[6..11] = onset per-string sums
__global__ void init_ws(float* __restrict__ ws) {
    if (threadIdx.x < 12) ws[threadIdx.x] = 0.0f;
}

__global__ __launch_bounds__(BDIM) void fret_kernel(const float* __restrict__ x,
                                                    const int* __restrict__ tgt,
                                                    float* __restrict__ ws) {
    const int blk   = blockIdx.x;
    const int chunk = blk % NCHUNK;
    const int bs    = blk / NCHUNK;          // b*Sn + s
    const int s     = bs % Sn;

    float local = 0.0f;
    const int t0 = chunk * TCHUNK;
    for (int t = t0 + threadIdx.x; t < t0 + TCHUNK; t += BDIM) {
        const long row = (long)bs * Tn + t;
        const float* p = x + row * Cn;
        float v[Cn];
        float m = -INFINITY;
        #pragma unroll
        for (int i = 0; i < Cn; ++i) { v[i] = p[i]; m = fmaxf(m, v[i]); }
        float sum = 0.0f;
        #pragma unroll
        for (int i = 0; i < Cn; ++i) sum += __expf(v[i] - m);
        const float lse = m + __logf(sum);
        const int c = tgt[row];
        local += lse - p[c];                 // re-read from L1, avoids dyn reg index
    }

    // wave reduce (64 lanes)
    #pragma unroll
    for (int off = 32; off > 0; off >>= 1)
        local += __shfl_down(local, off, 64);

    __shared__ float wsum[BDIM / 64];
    const int lane = threadIdx.x & 63, w = threadIdx.x >> 6;
    if (lane == 0) wsum[w] = local;
    __syncthreads();
    if (threadIdx.x == 0) {
        float bsum = 0.0f;
        #pragma unroll
        for (int i = 0; i < BDIM / 64; ++i) bsum += wsum[i];
        atomicAdd(&ws[s], bsum);
    }
}

__global__ __launch_bounds__(BDIM) void onset_kernel(const float* __restrict__ x,
                                                     const float* __restrict__ tg,
                                                     float* __restrict__ ws) {
    __shared__ float ls[Sn];
    if (threadIdx.x < Sn) ls[threadIdx.x] = 0.0f;
    __syncthreads();

    const int col = blockIdx.x * BDIM + threadIdx.x;   // s*Tn + t
    if (col < Sn * Tn) {
        const int s = col / Tn;
        float m = -INFINITY, sum = 0.0f, tsum = 0.0f, txsum = 0.0f;
        for (int b = 0; b < Bn; ++b) {
            const float xv = x[b * (Sn * Tn) + col];   // coalesced across lanes
            const float tv = tg[b * (Sn * Tn) + col];
            tsum  += tv;
            txsum += tv * xv;
            if (xv > m) { sum = sum * __expf(m - xv) + 1.0f; m = xv; }
            else        { sum += __expf(xv - m); }
        }
        const float on = tsum * (m + __logf(sum)) - txsum;
        atomicAdd(&ls[s], on);
    }
    __syncthreads();
    if (threadIdx.x < Sn) atomicAdd(&ws[6 + threadIdx.x], ls[threadIdx.x]);
}

__global__ void final_kernel(const float* __restrict__ ws, float* __restrict__ out) {
    if (threadIdx.x == 0) {
        float fs[Sn], os[Sn], fret = 0.0f, on = 0.0f;
        #pragma unroll
        for (int s = 0; s < Sn; ++s) {
            fs[s] = ws[s] * (1.0f / Bn);   // mean over batch
            os[s] = ws[6 + s];
            fret += fs[s];
            on   += os[s];
        }
        out[0] = 0.5f * fret + 0.5f * on;  // WEIGHT_FRET_ONSET = 0.5
        out[1] = fret;
        out[2] = on;
        #pragma unroll
        for (int s = 0; s < Sn; ++s) { out[3 + s] = fs[s]; out[9 + s] = os[s]; }
    }
}

extern "C" void kernel_launch(void* const* d_in, const int* in_sizes, int n_in,
                              void* d_out, int out_size, void* d_ws, size_t ws_size,
                              hipStream_t stream) {
    const float* output_fret  = (const float*)d_in[0];
    const int*   target_fret  = (const int*)d_in[1];
    const float* output_onset = (const float*)d_in[2];
    const float* target_onset = (const float*)d_in[3];
    float* ws  = (float*)d_ws;
    float* out = (float*)d_out;

    init_ws<<<1, 64, 0, stream>>>(ws);
    fret_kernel<<<Bn * Sn * NCHUNK, BDIM, 0, stream>>>(output_fret, target_fret, ws);
    onset_kernel<<<(Sn * Tn + BDIM - 1) / BDIM, BDIM, 0, stream>>>(output_onset, target_onset, ws);
    final_kernel<<<1, 64, 0, stream>>>(ws, out);
}

// Round 2
// 137.536 us; speedup vs baseline: 1.1517x; 1.1517x over previous
//
#include <hip/hip_runtime.h>
#include <math.h>

constexpr int Bn = 64, Sn = 6, Tn = 2000, Cn = 25;
constexpr int COLS  = Sn * Tn;            // 12000
constexpr int NQ    = Bn * Sn * Tn / 4;   // 192000 row-quads (4 rows = 25 float4)
constexpr int BDIM  = 256;
constexpr int QPB   = NQ / (BDIM);        // 750 blocks exactly
constexpr int BSPLIT = 4, BPC = Bn / BSPLIT;       // 4 chunks of 16 b's
constexpr int CBLK  = (COLS + BDIM - 1) / BDIM;    // 47

// d_ws layout:
//   float ws[0..5]  : per-string fret sums (atomics)
//   float ws[6..11] : per-string onset sums (atomics)
//   byte offset 64  : float4 part[BSPLIT][COLS] onset partials (768 KB)

__global__ void init_ws(float* __restrict__ ws) {
    if (threadIdx.x < 12) ws[threadIdx.x] = 0.0f;
}

#define V_ELEM(f) ((f & 3) == 0 ? v[(f) >> 2].x : \
                   (f & 3) == 1 ? v[(f) >> 2].y : \
                   (f & 3) == 2 ? v[(f) >> 2].z : v[(f) >> 2].w)

__global__ __launch_bounds__(BDIM) void fret_kernel(const float4* __restrict__ x4,
                                                    const int4* __restrict__ tgt4,
                                                    const float* __restrict__ x,
                                                    float* __restrict__ ws) {
    __shared__ float ls[Sn];
    if (threadIdx.x < Sn) ls[threadIdx.x] = 0.0f;
    __syncthreads();

    const int quad = blockIdx.x * BDIM + threadIdx.x;   // grid exact: 750*256 = 192000
    const float4* p = x4 + (long)quad * 25;             // 4 rows = 25 float4, 16B aligned
    float4 v[25];
    #pragma unroll
    for (int i = 0; i < 25; ++i) v[i] = p[i];
    const int4 tc = tgt4[quad];                          // 4 targets, coalesced 16B

    const float* rowbase = x + (long)quad * 100;
    float local = 0.0f;
    #pragma unroll
    for (int r = 0; r < 4; ++r) {
        float m = -INFINITY;
        #pragma unroll
        for (int c = 0; c < 25; ++c) { const int f = r * 25 + c; m = fmaxf(m, V_ELEM(f)); }
        float sum = 0.0f;
        #pragma unroll
        for (int c = 0; c < 25; ++c) { const int f = r * 25 + c; sum += __expf(V_ELEM(f) - m); }
        const int c = (r == 0 ? tc.x : r == 1 ? tc.y : r == 2 ? tc.z : tc.w);
        local += m + __logf(sum) - rowbase[r * 25 + c];  // scalar re-read, L1-warm
    }

    const int s = (quad / (Tn / 4)) % Sn;  // 500 quads per (b,s)
    atomicAdd(&ls[s], local);
    __syncthreads();
    if (threadIdx.x < Sn) atomicAdd(&ws[threadIdx.x], ls[threadIdx.x]);
}

__global__ __launch_bounds__(BDIM) void onset_pass1(const float* __restrict__ x,
                                                    const float* __restrict__ tg,
                                                    float4* __restrict__ part) {
    const int cb    = blockIdx.x % CBLK;
    const int chunk = blockIdx.x / CBLK;
    const int col   = cb * BDIM + threadIdx.x;
    if (col >= COLS) return;
    const int b0 = chunk * BPC;

    float xv[BPC], tsum = 0.0f, txsum = 0.0f;
    #pragma unroll
    for (int k = 0; k < BPC; ++k) {                      // 16 independent coalesced loads
        const float tv = tg[(b0 + k) * COLS + col];
        xv[k] = x[(b0 + k) * COLS + col];
        tsum  += tv;
        txsum += tv * xv[k];
    }
    float m = -INFINITY;
    #pragma unroll
    for (int k = 0; k < BPC; ++k) m = fmaxf(m, xv[k]);
    float sum = 0.0f;
    #pragma unroll
    for (int k = 0; k < BPC; ++k) sum += __expf(xv[k] - m);

    part[chunk * COLS + col] = make_float4(m, sum, tsum, txsum);
}

__global__ __launch_bounds__(BDIM) void onset_merge(const float4* __restrict__ part,
                                                    float* __restrict__ ws) {
    __shared__ float ls[Sn];
    if (threadIdx.x < Sn) ls[threadIdx.x] = 0.0f;
    __syncthreads();

    const int col = blockIdx.x * BDIM + threadIdx.x;
    if (col < COLS) {
        float M = -INFINITY, S = 0.0f, tsum = 0.0f, txsum = 0.0f;
        #pragma unroll
        for (int c = 0; c < BSPLIT; ++c) {
            const float4 pp = part[c * COLS + col];
            const float nm = fmaxf(M, pp.x);
            S = S * __expf(M - nm) + pp.y * __expf(pp.x - nm);
            M = nm;
            tsum += pp.z; txsum += pp.w;
        }
        const float on = tsum * (M + __logf(S)) - txsum;
        atomicAdd(&ls[col / Tn], on);
    }
    __syncthreads();
    if (threadIdx.x < Sn) atomicAdd(&ws[6 + threadIdx.x], ls[threadIdx.x]);
}

__global__ void final_kernel(const float* __restrict__ ws, float* __restrict__ out) {
    if (threadIdx.x == 0) {
        float fs[Sn], os[Sn], fret = 0.0f, on = 0.0f;
        #pragma unroll
        for (int s = 0; s < Sn; ++s) {
            fs[s] = ws[s] * (1.0f / Bn);
            os[s] = ws[6 + s];
            fret += fs[s];
            on   += os[s];
        }
        out[0] = 0.5f * fret + 0.5f * on;
        out[1] = fret;
        out[2] = on;
        #pragma unroll
        for (int s = 0; s < Sn; ++s) { out[3 + s] = fs[s]; out[9 + s] = os[s]; }
    }
}

extern "C" void kernel_launch(void* const* d_in, const int* in_sizes, int n_in,
                              void* d_out, int out_size, void* d_ws, size_t ws_size,
                              hipStream_t stream) {
    const float* output_fret  = (const float*)d_in[0];
    const int*   target_fret  = (const int*)d_in[1];
    const float* output_onset = (const float*)d_in[2];
    const float* target_onset = (const float*)d_in[3];
    float*  ws   = (float*)d_ws;
    float4* part = (float4*)((char*)d_ws + 64);
    float*  out  = (float*)d_out;

    init_ws<<<1, 64, 0, stream>>>(ws);
    fret_kernel<<<QPB, BDIM, 0, stream>>>((const float4*)output_fret,
                                          (const int4*)target_fret, output_fret, ws);
    onset_pass1<<<CBLK * BSPLIT, BDIM, 0, stream>>>(output_onset, target_onset, part);
    onset_merge<<<CBLK, BDIM, 0, stream>>>(part, ws);
    final_kernel<<<1, 64, 0, stream>>>(ws, out);
}

// Round 3
// 136.494 us; speedup vs baseline: 1.1605x; 1.0076x over previous
//
#include <hip/hip_runtime.h>
#include <math.h>

constexpr int Bn = 64, Sn = 6, Tn = 2000, Cn = 25;
constexpr int COLS = Sn * Tn;              // 12000
constexpr int ROWS = Bn * Sn * Tn;         // 768000
constexpr int BDIM = 256;
constexpr int RPB  = 256;                  // rows per fret block
constexpr int FBLK = ROWS / RPB;           // 3000 fret blocks (exact)
constexpr int OBLK = (COLS + BDIM - 1) / BDIM;  // 47 onset blocks
constexpr int GRID = FBLK + OBLK;          // 3047

// d_ws layout: pf[FBLK*6] fret per-block per-string partials (72 KB),
//              po[OBLK*6] onset per-block per-string partials (1.1 KB)

__global__ __launch_bounds__(BDIM) void main_kernel(const float4* __restrict__ x4,
                                                    const int*    __restrict__ tgt,
                                                    const float*  __restrict__ ox,
                                                    const float*  __restrict__ ot,
                                                    float* __restrict__ pf,
                                                    float* __restrict__ po) {
    __shared__ float lds[RPB * Cn];        // 25.6 KB row stage (fret path only)
    __shared__ float ls[Sn];
    const int tid = threadIdx.x;
    if (tid < Sn) ls[tid] = 0.0f;

    if (blockIdx.x < OBLK) {
        // ---------------- onset path: softmax over B per column ----------------
        __syncthreads();
        const int col = blockIdx.x * BDIM + tid;
        if (col < COLS) {
            float M = -INFINITY, S = 0.0f, ts = 0.0f, txs = 0.0f;
            for (int b0 = 0; b0 < Bn; b0 += 16) {
                float xv[16];
                #pragma unroll
                for (int k = 0; k < 16; ++k) xv[k] = ox[(b0 + k) * COLS + col];
                #pragma unroll
                for (int k = 0; k < 16; ++k) {
                    const float tv = ot[(b0 + k) * COLS + col];
                    ts  += tv;
                    txs += tv * xv[k];
                }
                float cm = -INFINITY;
                #pragma unroll
                for (int k = 0; k < 16; ++k) cm = fmaxf(cm, xv[k]);
                float cs = 0.0f;
                #pragma unroll
                for (int k = 0; k < 16; ++k) cs += __expf(xv[k] - cm);
                const float nm = fmaxf(M, cm);
                S = S * __expf(M - nm) + cs * __expf(cm - nm);   // exp(-inf)=0 first iter
                M = nm;
            }
            const float on = ts * (M + __logf(S)) - txs;
            atomicAdd(&ls[col / Tn], on);
        }
        __syncthreads();
        if (tid < Sn) po[blockIdx.x * Sn + tid] = ls[tid];
    } else {
        // ---------------- fret path: CE over 25 classes per row ----------------
        const int fb = blockIdx.x - OBLK;
        // stage 256 rows = 1600 float4, fully coalesced
        const float4* src = x4 + (long)fb * (RPB * Cn / 4);
        float4* lds4 = (float4*)lds;
        #pragma unroll
        for (int k = tid; k < RPB * Cn / 4; k += BDIM) lds4[k] = src[k];
        __syncthreads();

        const int   row   = fb * RPB + tid;
        const float* myrow = lds + tid * Cn;        // stride 25: free 2-way aliasing
        float m = -INFINITY;
        #pragma unroll
        for (int c = 0; c < Cn; ++c) m = fmaxf(m, myrow[c]);
        float sum = 0.0f;
        #pragma unroll
        for (int c = 0; c < Cn; ++c) sum += __expf(myrow[c] - m);
        const float nll = m + __logf(sum) - myrow[tgt[row]];

        const int s = (row / Tn) % Sn;
        atomicAdd(&ls[s], nll);                     // ds_add_f32
        __syncthreads();
        if (tid < Sn) pf[fb * Sn + tid] = ls[tid];
    }
}

__global__ __launch_bounds__(256) void finish_kernel(const float* __restrict__ pf,
                                                     const float* __restrict__ po,
                                                     float* __restrict__ out) {
    __shared__ float acc[2 * Sn];
    const int tid = threadIdx.x;
    if (tid < 2 * Sn) acc[tid] = 0.0f;
    __syncthreads();

    float fs[Sn] = {0, 0, 0, 0, 0, 0};
    for (int blk = tid; blk < FBLK; blk += 256) {
        #pragma unroll
        for (int s = 0; s < Sn; ++s) fs[s] += pf[blk * Sn + s];
    }
    #pragma unroll
    for (int s = 0; s < Sn; ++s) atomicAdd(&acc[s], fs[s]);
    for (int i = tid; i < OBLK * Sn; i += 256) atomicAdd(&acc[Sn + i % Sn], po[i]);
    __syncthreads();

    if (tid == 0) {
        float fret = 0.0f, on = 0.0f, fsv[Sn], osv[Sn];
        #pragma unroll
        for (int s = 0; s < Sn; ++s) {
            fsv[s] = acc[s] * (1.0f / Bn);          // mean over batch
            osv[s] = acc[Sn + s];
            fret += fsv[s];
            on   += osv[s];
        }
        out[0] = 0.5f * fret + 0.5f * on;           // WEIGHT_FRET_ONSET = 0.5
        out[1] = fret;
        out[2] = on;
        #pragma unroll
        for (int s = 0; s < Sn; ++s) { out[3 + s] = fsv[s]; out[9 + s] = osv[s]; }
    }
}

extern "C" void kernel_launch(void* const* d_in, const int* in_sizes, int n_in,
                              void* d_out, int out_size, void* d_ws, size_t ws_size,
                              hipStream_t stream) {
    const float* output_fret  = (const float*)d_in[0];
    const int*   target_fret  = (const int*)d_in[1];
    const float* output_onset = (const float*)d_in[2];
    const float* target_onset = (const float*)d_in[3];
    float* pf  = (float*)d_ws;
    float* po  = pf + FBLK * Sn;
    float* out = (float*)d_out;

    main_kernel<<<GRID, BDIM, 0, stream>>>((const float4*)output_fret, target_fret,
                                           output_onset, target_onset, pf, po);
    finish_kernel<<<1, 256, 0, stream>>>(pf, po, out);
}

// Round 4
// 126.441 us; speedup vs baseline: 1.2527x; 1.0795x over previous
//
#include <hip/hip_runtime.h>
#include <math.h>

constexpr int Bn = 64, Sn = 6, Tn = 2000, Cn = 25;
constexpr int COLS = Sn * Tn;              // 12000
constexpr int ROWS = Bn * Sn * Tn;         // 768000
constexpr int BDIM = 256;
constexpr int RPB  = 256;                  // rows per fret block
constexpr int FBLK = ROWS / RPB;           // 3000 fret blocks (exact)
constexpr int FPAD = 3072;                 // padded leading dim for pf
constexpr int OBLK = (COLS + BDIM - 1) / BDIM;  // 47 onset blocks
constexpr int OPAD = 64;
constexpr int GRID = FBLK + OBLK;          // 3047

// d_ws layout: pf[Sn][FPAD] fret per-string per-block partials (72 KB, transposed
//              for coalesced finish reads), then po[Sn][OPAD] onset partials.

__global__ __launch_bounds__(BDIM) void main_kernel(const float4* __restrict__ x4,
                                                    const int*    __restrict__ tgt,
                                                    const float*  __restrict__ ox,
                                                    const float*  __restrict__ ot,
                                                    float* __restrict__ pf,
                                                    float* __restrict__ po) {
    __shared__ float lds[RPB * Cn];        // 25.6 KB row stage (fret path only)
    __shared__ float ls[Sn];
    const int tid = threadIdx.x;
    if (tid < Sn) ls[tid] = 0.0f;

    if (blockIdx.x < OBLK) {
        // ---------------- onset path: softmax over B per column ----------------
        __syncthreads();
        const int col = blockIdx.x * BDIM + tid;
        if (col < COLS) {
            float M = -INFINITY, S = 0.0f, ts = 0.0f, txs = 0.0f;
            for (int b0 = 0; b0 < Bn; b0 += 16) {
                float xv[16];
                #pragma unroll
                for (int k = 0; k < 16; ++k) xv[k] = ox[(b0 + k) * COLS + col];
                #pragma unroll
                for (int k = 0; k < 16; ++k) {
                    const float tv = ot[(b0 + k) * COLS + col];
                    ts  += tv;
                    txs += tv * xv[k];
                }
                float cm = -INFINITY;
                #pragma unroll
                for (int k = 0; k < 16; ++k) cm = fmaxf(cm, xv[k]);
                float cs = 0.0f;
                #pragma unroll
                for (int k = 0; k < 16; ++k) cs += __expf(xv[k] - cm);
                const float nm = fmaxf(M, cm);
                S = S * __expf(M - nm) + cs * __expf(cm - nm);   // exp(-inf)=0 first iter
                M = nm;
            }
            const float on = ts * (M + __logf(S)) - txs;
            atomicAdd(&ls[col / Tn], on);
        }
        __syncthreads();
        if (tid < Sn) po[tid * OPAD + blockIdx.x] = ls[tid];
    } else {
        // ---------------- fret path: CE over 25 classes per row ----------------
        const int fb = blockIdx.x - OBLK;
        // stage 256 rows = 1600 float4, fully coalesced
        const float4* src = x4 + (long)fb * (RPB * Cn / 4);
        float4* lds4 = (float4*)lds;
        #pragma unroll
        for (int k = tid; k < RPB * Cn / 4; k += BDIM) lds4[k] = src[k];
        __syncthreads();

        const int   row   = fb * RPB + tid;
        const float* myrow = lds + tid * Cn;        // stride 25: free 2-way aliasing
        float m = -INFINITY;
        #pragma unroll
        for (int c = 0; c < Cn; ++c) m = fmaxf(m, myrow[c]);
        float sum = 0.0f;
        #pragma unroll
        for (int c = 0; c < Cn; ++c) sum += __expf(myrow[c] - m);
        const float nll = m + __logf(sum) - myrow[tgt[row]];

        const int s = (row / Tn) % Sn;
        atomicAdd(&ls[s], nll);                     // ds_add_f32, 6 addresses
        __syncthreads();
        if (tid < Sn) pf[tid * FPAD + fb] = ls[tid];
    }
}

__global__ __launch_bounds__(1024) void finish_kernel(const float* __restrict__ pf,
                                                      const float* __restrict__ po,
                                                      float* __restrict__ out) {
    __shared__ float acc[2 * Sn];
    const int tid  = threadIdx.x;
    const int lane = tid & 63;
    if (tid < 2 * Sn) acc[tid] = 0.0f;
    __syncthreads();

    // ---- fret partials: 6 coalesced strided sweeps, wave-butterfly reduce ----
    float fs[Sn];
    #pragma unroll
    for (int s = 0; s < Sn; ++s) {
        float v = 0.0f;
        for (int i = tid; i < FBLK; i += 1024) v += pf[s * FPAD + i];  // coalesced
        fs[s] = v;
    }
    #pragma unroll
    for (int off = 32; off > 0; off >>= 1) {
        #pragma unroll
        for (int s = 0; s < Sn; ++s) fs[s] += __shfl_xor(fs[s], off, 64);
    }
    if (lane == 0) {
        #pragma unroll
        for (int s = 0; s < Sn; ++s) atomicAdd(&acc[s], fs[s]);   // 16 waves x 6
    }

    // ---- onset partials: wave w sums string w (47 entries) ----
    const int w = tid >> 6;
    if (w < Sn) {
        float v = (lane < OBLK) ? po[w * OPAD + lane] : 0.0f;
        #pragma unroll
        for (int off = 32; off > 0; off >>= 1) v += __shfl_xor(v, off, 64);
        if (lane == 0) acc[Sn + w] = v;
    }
    __syncthreads();

    if (tid == 0) {
        float fret = 0.0f, on = 0.0f, fsv[Sn], osv[Sn];
        #pragma unroll
        for (int s = 0; s < Sn; ++s) {
            fsv[s] = acc[s] * (1.0f / Bn);          // mean over batch
            osv[s] = acc[Sn + s];
            fret += fsv[s];
            on   += osv[s];
        }
        out[0] = 0.5f * fret + 0.5f * on;           // WEIGHT_FRET_ONSET = 0.5
        out[1] = fret;
        out[2] = on;
        #pragma unroll
        for (int s = 0; s < Sn; ++s) { out[3 + s] = fsv[s]; out[9 + s] = osv[s]; }
    }
}

extern "C" void kernel_launch(void* const* d_in, const int* in_sizes, int n_in,
                              void* d_out, int out_size, void* d_ws, size_t ws_size,
                              hipStream_t stream) {
    const float* output_fret  = (const float*)d_in[0];
    const int*   target_fret  = (const int*)d_in[1];
    const float* output_onset = (const float*)d_in[2];
    const float* target_onset = (const float*)d_in[3];
    float* pf  = (float*)d_ws;                 // [Sn][FPAD]
    float* po  = pf + Sn * FPAD;               // [Sn][OPAD]
    float* out = (float*)d_out;

    main_kernel<<<GRID, BDIM, 0, stream>>>((const float4*)output_fret, target_fret,
                                           output_onset, target_onset, pf, po);
    finish_kernel<<<1, 1024, 0, stream>>>(pf, po, out);
}